// Round 8
// baseline (114.160 us; speedup 1.0000x reference)
//
#include <hip/hip_runtime.h>

#define EPSV 1e-5f

#if defined(__has_builtin)
#if __has_builtin(__builtin_amdgcn_fdot2)
#define HAS_FDOT2 1
#endif
#endif

typedef __fp16 half2v __attribute__((ext_vector_type(2)));

__device__ __forceinline__ half2v u32_as_h2(unsigned u) {
    union { unsigned u; half2v h; } cv;
    cv.u = u;
    return cv.h;
}

// ---------------------------------------------------------------------------
// Kernel 1: fold the 3 branches into one 13x13 kernel + bias. Emits the f32
// kernel (wf, fallback) and f16-packed weight pairs (wpk): per channel, per
// tap-row ky: 7 u32 = half2(w[2k], w[2k+1]) with w[13]=0.
// ---------------------------------------------------------------------------
__global__ __launch_bounds__(256) void fuse_weights(
    const float* __restrict__ w_large, const float* __restrict__ w_small,
    const float* __restrict__ g_l, const float* __restrict__ b_l,
    const float* __restrict__ m_l, const float* __restrict__ v_l,
    const float* __restrict__ g_s, const float* __restrict__ b_s,
    const float* __restrict__ m_s, const float* __restrict__ v_s,
    const float* __restrict__ g_i, const float* __restrict__ b_i,
    const float* __restrict__ m_i, const float* __restrict__ v_i,
    float* __restrict__ wf, float* __restrict__ bf,
    unsigned* __restrict__ wpk) {
    __shared__ float sw[169];
    const int c = blockIdx.x;
    const int t = threadIdx.x;
    const float sl = g_l[c] * rsqrtf(v_l[c] + EPSV);
    const float ss = g_s[c] * rsqrtf(v_s[c] + EPSV);
    const float si = g_i[c] * rsqrtf(v_i[c] + EPSV);
    if (t < 169) {
        const int ky = t / 13, kx = t % 13;
        float w = w_large[c * 169 + t] * sl;
        if (ky >= 5 && ky <= 7 && kx >= 5 && kx <= 7)
            w += w_small[c * 9 + (ky - 5) * 3 + (kx - 5)] * ss;
        if (t == 6 * 13 + 6) w += si;
        wf[c * 169 + t] = w;
        sw[t] = w;
    }
    if (t == 0)
        bf[c] = (b_l[c] - m_l[c] * sl) + (b_s[c] - m_s[c] * ss) +
                (b_i[c] - m_i[c] * si);
    __syncthreads();
    if (t < 91) {  // 13 rows x 7 pairs
        const int ky = t / 7, k2 = t % 7;
        const float w0 = sw[ky * 13 + 2 * k2];
        const float w1 = (2 * k2 + 1 < 13) ? sw[ky * 13 + 2 * k2 + 1] : 0.0f;
        const half2v h = __builtin_amdgcn_cvt_pkrtz(w0, w1);
        union { half2v h; unsigned u; } cv;
        cv.h = h;
        wpk[c * 91 + t] = cv.u;
    }
}

// ---------------------------------------------------------------------------
// Kernel 2: depthwise 13x13 + bias, [16,384,64,64] f32. No LDS. 256 thr/blk,
// ONE image per block (L1-resident, c wave-uniform -> scalar weights).
// Thread (rg=t>>4, cg=t&15) computes a 4x4 output block: acc 16 + pairs 18
// + window 20 transient fits the 80-VGPR cap of __launch_bounds__(256,6) ->
// no AGPR accumulator traffic, 6 waves/SIMD ceiling. Per input row (19):
// 5 global dwordx4 (cols c0-8..c0+11); halo via 64-bit pointer cndmask to a
// zero row. Inner product: v_dot2_f32_f16, 7 per (row, out-col).
// ---------------------------------------------------------------------------
__global__ __launch_bounds__(256, 6) void dwconv13(
    const float* __restrict__ x, const float* __restrict__ wff,
    const unsigned* __restrict__ wpk, const float* __restrict__ bf,
    const float* __restrict__ zrow, float* __restrict__ out) {
    const int t = threadIdx.x;           // 0..255
    const int img = blockIdx.x;          // n*384 + c
    const int c = __builtin_amdgcn_readfirstlane(img % 384);
    const size_t base = (size_t)img * 4096;
    const int rg = t >> 4;               // 0..15 -> rows 4*rg..4*rg+3
    const int cg = t & 15;               // 0..15 -> cols 4*cg..4*cg+3
    const int r0 = rg << 2;
    const int c0 = cg << 2;

    const float* __restrict__ imgp = x + base;
    const float bv = bf[c];

    // loop-invariant chunk offsets/validity (window cols c0-8 .. c0+11)
    int cb[5];
    bool colok[5];
#pragma unroll
    for (int q = 0; q < 5; ++q) {
        const int cbv = c0 - 8 + 4 * q;          // -8..68
        colok[q] = (cbv >= 0) && (cbv <= 60);
        cb[q] = cbv;
    }

    float acc[4][4];
#pragma unroll
    for (int i = 0; i < 4; ++i)
#pragma unroll
        for (int j = 0; j < 4; ++j) acc[i][j] = bv;

#ifdef HAS_FDOT2
    const unsigned* __restrict__ wc = wpk + c * 91;
    half2v ep[9], op[9];                 // use [1..8]
#else
    const float* __restrict__ wc = wff + c * 169;
#endif

#pragma unroll 1
    for (int dr = 0; dr < 19; ++dr) {
        const int riy = r0 + dr - 6;             // -6..72
        const bool rowok = ((unsigned)riy) < 64u;
        const float* rb = imgp + (riy << 6);

        float xf[20];
#pragma unroll
        for (int q = 0; q < 5; ++q) {
            const float* p = (rowok && colok[q]) ? (rb + cb[q]) : zrow;
            const float4 v = *(const float4*)p;
            xf[4 * q + 0] = v.x;
            xf[4 * q + 1] = v.y;
            xf[4 * q + 2] = v.z;
            xf[4 * q + 3] = v.w;
        }

#ifdef HAS_FDOT2
#pragma unroll
        for (int m = 1; m <= 8; ++m) {
            ep[m] = __builtin_amdgcn_cvt_pkrtz(xf[2 * m], xf[2 * m + 1]);
            op[m] = __builtin_amdgcn_cvt_pkrtz(xf[2 * m + 1], xf[2 * m + 2]);
        }
#pragma unroll
        for (int i = 0; i < 4; ++i) {
            const int ky = dr - i;               // wave-uniform
            if (ky >= 0 && ky <= 12) {
                const unsigned* wr = wc + ky * 7;
#pragma unroll
                for (int j = 0; j < 4; ++j) {
                    float a = acc[i][j];
                    if (j & 1) {
                        const int b = (j + 1) >> 1;
#pragma unroll
                        for (int k = 0; k < 7; ++k)
                            a = __builtin_amdgcn_fdot2(op[b + k],
                                                       u32_as_h2(wr[k]), a,
                                                       false);
                    } else {
                        const int b = (j >> 1) + 1;
#pragma unroll
                        for (int k = 0; k < 7; ++k)
                            a = __builtin_amdgcn_fdot2(ep[b + k],
                                                       u32_as_h2(wr[k]), a,
                                                       false);
                    }
                    acc[i][j] = a;
                }
            }
        }
#else
#pragma unroll
        for (int i = 0; i < 4; ++i) {
            const int ky = dr - i;
            if (ky >= 0 && ky <= 12) {
                const float* wr = wc + ky * 13;
#pragma unroll
                for (int dc = 0; dc < 13; ++dc) {
                    const float w = wr[dc];
#pragma unroll
                    for (int j = 0; j < 4; ++j)
                        acc[i][j] = fmaf(xf[j + dc + 2], w, acc[i][j]);
                }
            }
        }
#endif
    }

    float* ob = out + base + (size_t)r0 * 64 + c0;
#pragma unroll
    for (int i = 0; i < 4; ++i)
        *(float4*)(ob + i * 64) =
            make_float4(acc[i][0], acc[i][1], acc[i][2], acc[i][3]);
}

// ---------------------------------------------------------------------------
extern "C" void kernel_launch(void* const* d_in, const int* in_sizes, int n_in,
                              void* d_out, int out_size, void* d_ws,
                              size_t ws_size, hipStream_t stream) {
    const float* x = (const float*)d_in[0];
    const float* w_large = (const float*)d_in[1];
    const float* w_small = (const float*)d_in[2];
    const float* g_l = (const float*)d_in[3];
    const float* b_l = (const float*)d_in[4];
    const float* m_l = (const float*)d_in[5];
    const float* v_l = (const float*)d_in[6];
    const float* g_s = (const float*)d_in[7];
    const float* b_s = (const float*)d_in[8];
    const float* m_s = (const float*)d_in[9];
    const float* v_s = (const float*)d_in[10];
    const float* g_i = (const float*)d_in[11];
    const float* b_i = (const float*)d_in[12];
    const float* m_i = (const float*)d_in[13];
    const float* v_i = (const float*)d_in[14];
    float* outp = (float*)d_out;

    // ws layout (floats): zimg[4096] | wf[64896] | bf[384] | wpk[34944 u32]
    float* zimg = (float*)d_ws;
    float* wfp = zimg + 4096;
    float* bfp = wfp + 64896;
    unsigned* wpk = (unsigned*)(bfp + 384);

    (void)hipMemsetAsync(zimg, 0, 4096 * sizeof(float), stream);
    fuse_weights<<<384, 256, 0, stream>>>(w_large, w_small, g_l, b_l, m_l, v_l,
                                          g_s, b_s, m_s, v_s, g_i, b_i, m_i,
                                          v_i, wfp, bfp, wpk);
    dwconv13<<<16 * 384, 256, 0, stream>>>(x, wfp, wpk, bfp, zimg, outp);
}